// Round 3
// baseline (183.455 us; speedup 1.0000x reference)
//
#include <hip/hip_runtime.h>
#include <stdint.h>

// Sudoku naked-pair elimination as 9-bit candidate-set logic.
// mask: [B, 9 digit, 9 row, 9 col] fp32 binary, B = 32768 (729 floats/batch).
//
// Round-3 structure:
//   Phase A: float4 coalesced load -> LDS bytes (0/1 per element), flat layout.
//   Phase B: one thread per 3x3 box: read its 81 bytes, build 9 cell masks,
//            naked-pair analysis ONCE per box, write 81 result bytes back to
//            the SAME LDS bytes (safe: boxes partition cells; read-before-write
//            within thread).
//   Phase C: LDS uint32 -> float4 coalesced store. No div/mod anywhere hot.

#define NB 16                  // batches per block (divides 32768)
#define ELEMS (NB * 729)       // 11664 floats per block
#define NWORDS (ELEMS / 4)     // 2916 float4 / byte4 words (46656 B, 16B-aligned)
#define NBOX (NB * 9)          // 144 boxes per block

__global__ __launch_bounds__(256) void sudoku_naked_pair_kernel(
    const float* __restrict__ mask, float* __restrict__ out) {
  __shared__ uint32_t lds32[NWORDS];   // 11664 B: input bits, then output bits
  uint8_t* lds8 = (uint8_t*)lds32;

  const int tid = threadIdx.x;
  const size_t base = (size_t)blockIdx.x * ELEMS;

  // ---- Phase A: coalesced float4 load, pack 4 elements -> 1 LDS dword
  const float4* in4 = (const float4*)(mask + base);
  for (int i = tid; i < NWORDS; i += 256) {
    float4 v = in4[i];
    lds32[i] = (uint32_t)(v.x != 0.0f)
             | ((uint32_t)(v.y != 0.0f) << 8)
             | ((uint32_t)(v.z != 0.0f) << 16)
             | ((uint32_t)(v.w != 0.0f) << 24);
  }
  __syncthreads();

  // ---- Phase B: one thread per box, full pipeline in registers
  if (tid < NBOX) {
    const int b = tid / 9, bi = tid - b * 9;
    const int boxbase = b * 729 + (bi / 3) * 27 + (bi % 3) * 3;

    uint32_t cellm[9] = {0, 0, 0, 0, 0, 0, 0, 0, 0};
#pragma unroll
    for (int d = 0; d < 9; ++d) {
      const uint8_t* p = lds8 + boxbase + d * 81;
#pragma unroll
      for (int r = 0; r < 3; ++r)
#pragma unroll
        for (int c = 0; c < 3; ++c)
          cellm[r * 3 + c] |= ((uint32_t)p[r * 9 + c] & 1u) << d;
    }

    uint32_t pairm[9];
#pragma unroll
    for (int j = 0; j < 9; ++j)
      pairm[j] = (__popc(cellm[j]) == 2) ? cellm[j] : 0u;

    bool naked[9];
#pragma unroll
    for (int j = 0; j < 9; ++j) {
      int cnt = 0;
#pragma unroll
      for (int k = 0; k < 9; ++k) cnt += (pairm[k] == pairm[j]);
      naked[j] = (pairm[j] != 0u) && (cnt == 2);  // exactly-2 cells hold pair j
    }

#pragma unroll
    for (int j = 0; j < 9; ++j) {
      uint32_t er = 0;
#pragma unroll
      for (int k = 0; k < 9; ++k)
        if (naked[k] && pairm[k] != pairm[j]) er |= pairm[k];
      cellm[j] &= ~er;  // final candidate set for cell j
    }

    // write result bits back to the SAME flat byte layout (read-before-write
    // within this thread; other threads never touch this box's bytes)
#pragma unroll
    for (int d = 0; d < 9; ++d) {
      uint8_t* p = lds8 + boxbase + d * 81;
#pragma unroll
      for (int r = 0; r < 3; ++r)
#pragma unroll
        for (int c = 0; c < 3; ++c)
          p[r * 9 + c] = (uint8_t)((cellm[r * 3 + c] >> d) & 1u);
    }
  }
  __syncthreads();

  // ---- Phase C: LDS dword -> float4 coalesced store (div/mod-free)
  float4* out4 = (float4*)(out + base);
  for (int i = tid; i < NWORDS; i += 256) {
    uint32_t w = lds32[i];
    float4 v;
    v.x = (float)(w & 0xFFu);
    v.y = (float)((w >> 8) & 0xFFu);
    v.z = (float)((w >> 16) & 0xFFu);
    v.w = (float)(w >> 24);
    out4[i] = v;
  }
}

extern "C" void kernel_launch(void* const* d_in, const int* in_sizes, int n_in,
                              void* d_out, int out_size, void* d_ws, size_t ws_size,
                              hipStream_t stream) {
  const float* mask = (const float*)d_in[0];
  // d_in[1] (enc) / d_in[2] (dec) are the fixed pair matrices; semantics hardcoded.
  float* out = (float*)d_out;
  const int B = in_sizes[0] / 729;  // 32768
  const int grid = B / NB;          // 2048
  sudoku_naked_pair_kernel<<<grid, 256, 0, stream>>>(mask, out);
}

// Round 4
// 179.619 us; speedup vs baseline: 1.0214x; 1.0214x over previous
//
#include <hip/hip_runtime.h>
#include <stdint.h>

// Sudoku naked-pair elimination as 9-bit candidate-set logic.
// mask: [B, 9 digit, 9 row, 9 col] fp32 binary, B = 32768 (729 floats/batch).
//
// Round-4: round-2 structure (thread<->cell, one thread per box for analysis)
// + deep MLP (all loads issued before any dependent use, single wait per
// phase) + nontemporal streaming loads/stores (data touched exactly once).

#define NB 8                    // batches per block
#define NCELL (NB * 81)         // 648 cells per block
#define NBOX (NB * 9)           // 72 boxes per block

__global__ __launch_bounds__(256) void sudoku_naked_pair_kernel(
    const float* __restrict__ mask, float* __restrict__ out) {
  __shared__ unsigned short pairm[NCELL];  // exact-pair mask per cell (0 if none)
  __shared__ unsigned short erls[NCELL];   // per-cell erase mask

  const int tid = threadIdx.x;
  const size_t base = (size_t)blockIdx.x * (NB * 729);

  // thread owns cells tid, tid+256, tid+512 (third only for tid < 136)
  const int c0 = tid, c1 = tid + 256, c2 = tid + 512;
  const bool has3 = (c2 < NCELL);
  const int b0 = c0 / 81, cell0 = c0 - b0 * 81;
  const int b1 = c1 / 81, cell1 = c1 - b1 * 81;
  const int b2 = c2 / 81, cell2 = c2 - b2 * 81;
  const float* p0 = mask + base + b0 * 729 + cell0;
  const float* p1 = mask + base + b1 * 729 + cell1;
  const float* p2 = mask + base + b2 * 729 + cell2;

  // ---- Phase 1a: issue ALL loads first (deep MLP, one latency exposure)
  float v0[9], v1[9], v2[9];
#pragma unroll
  for (int d = 0; d < 9; ++d) v0[d] = __builtin_nontemporal_load(p0 + d * 81);
#pragma unroll
  for (int d = 0; d < 9; ++d) v1[d] = __builtin_nontemporal_load(p1 + d * 81);
  if (has3) {
#pragma unroll
    for (int d = 0; d < 9; ++d) v2[d] = __builtin_nontemporal_load(p2 + d * 81);
  }

  // ---- Phase 1b: build candidate masks, publish pair masks
  uint32_t m0 = 0, m1 = 0, m2 = 0;
#pragma unroll
  for (int d = 0; d < 9; ++d) {
    m0 |= (v0[d] != 0.0f ? 1u : 0u) << d;
    m1 |= (v1[d] != 0.0f ? 1u : 0u) << d;
  }
  pairm[c0] = (unsigned short)((__popc(m0) == 2) ? m0 : 0u);
  pairm[c1] = (unsigned short)((__popc(m1) == 2) ? m1 : 0u);
  if (has3) {
#pragma unroll
    for (int d = 0; d < 9; ++d) m2 |= (v2[d] != 0.0f ? 1u : 0u) << d;
    pairm[c2] = (unsigned short)((__popc(m2) == 2) ? m2 : 0u);
  }
  __syncthreads();

  // ---- Phase 2: one thread per box — naked-pair analysis once per box
  if (tid < NBOX) {
    const int b = tid / 9, bi = tid - b * 9;
    const int bb = b * 81 + (bi / 3) * 27 + (bi % 3) * 3;  // box top-left cell
    uint32_t pm[9];
#pragma unroll
    for (int j = 0; j < 3; ++j) {
      pm[3 * j + 0] = pairm[bb + 9 * j + 0];
      pm[3 * j + 1] = pairm[bb + 9 * j + 1];
      pm[3 * j + 2] = pairm[bb + 9 * j + 2];
    }
    bool naked[9];
#pragma unroll
    for (int j = 0; j < 9; ++j) {
      int cnt = 0;
#pragma unroll
      for (int k = 0; k < 9; ++k) cnt += (pm[k] == pm[j]);
      naked[j] = (pm[j] != 0u) && (cnt == 2);
    }
#pragma unroll
    for (int j = 0; j < 9; ++j) {
      uint32_t er = 0;
#pragma unroll
      for (int k = 0; k < 9; ++k)
        if (naked[k] && pm[k] != pm[j]) er |= pm[k];
      erls[bb + 9 * (j / 3) + (j % 3)] = (unsigned short)er;
    }
  }
  __syncthreads();

  // ---- Phase 3: compute all outputs, then burst nontemporal stores
  const uint32_t f0 = m0 & ~(uint32_t)erls[c0];
  const uint32_t f1 = m1 & ~(uint32_t)erls[c1];
  const uint32_t f2 = has3 ? (m2 & ~(uint32_t)erls[c2]) : 0u;
  float* q0 = out + base + b0 * 729 + cell0;
  float* q1 = out + base + b1 * 729 + cell1;
  float* q2 = out + base + b2 * 729 + cell2;
#pragma unroll
  for (int d = 0; d < 9; ++d)
    __builtin_nontemporal_store((float)((f0 >> d) & 1u), q0 + d * 81);
#pragma unroll
  for (int d = 0; d < 9; ++d)
    __builtin_nontemporal_store((float)((f1 >> d) & 1u), q1 + d * 81);
  if (has3) {
#pragma unroll
    for (int d = 0; d < 9; ++d)
      __builtin_nontemporal_store((float)((f2 >> d) & 1u), q2 + d * 81);
  }
}

extern "C" void kernel_launch(void* const* d_in, const int* in_sizes, int n_in,
                              void* d_out, int out_size, void* d_ws, size_t ws_size,
                              hipStream_t stream) {
  const float* mask = (const float*)d_in[0];
  // d_in[1] (enc) / d_in[2] (dec) are the fixed pair matrices; semantics hardcoded.
  float* out = (float*)d_out;
  const int B = in_sizes[0] / 729;  // 32768
  const int grid = B / NB;          // 4096
  sudoku_naked_pair_kernel<<<grid, 256, 0, stream>>>(mask, out);
}